// Round 2
// baseline (261.347 us; speedup 1.0000x reference)
//
#include <hip/hip_runtime.h>
#include <math.h>

#define BB 16
#define HH 512
#define WW 512
#define CC 4

#define SEGS 32
#define RPT  (HH / SEGS)      // 16 rows per thread in K1
#define RROWS 4               // rows per block in K2

// ---------------------------------------------------------------------------
// Kernel 1: read defgrad once (float2), compute logistic for both channels,
// write dgx plane (for K2's row scan) and ys = column-inclusive-scan of dgy.
// grid: BB*(WW/32) = 256 blocks x 1024 threads (32 cols x 32 h-segments).
// ---------------------------------------------------------------------------
__global__ __launch_bounds__(1024)
void prep_colscan_kernel(const float2* __restrict__ defgrad,
                         float* __restrict__ dgx, int dgx_stride,
                         float* __restrict__ ys,  int ys_stride) {
    const int wt  = blockIdx.x % (WW / 32);
    const int b   = blockIdx.x / (WW / 32);
    const int col = threadIdx.x & 31;
    const int seg = threadIdx.x >> 5;          // 0..31
    const int w   = wt * 32 + col;
    const int h0  = seg * RPT;
    const float2* dg = defgrad + (size_t)b * HH * WW;
    const size_t rowbase = ((size_t)b * HH + h0) * WW + w;

    float vals[RPT];
    float s = 0.f;
#pragma unroll
    for (int i = 0; i < RPT; ++i) {
        float2 v = dg[(size_t)(h0 + i) * WW + w];
        float gx = 2.0f / (1.0f + expf(-v.x));
        float gy = 2.0f / (1.0f + expf(-v.y));
        dgx[(rowbase + (size_t)i * WW) * (size_t)dgx_stride] = gx;
        vals[i] = gy;
        s += gy;
    }

    __shared__ float part[SEGS][32];
    part[seg][col] = s;
    __syncthreads();

    float run = 0.f;
    for (int j = 0; j < seg; ++j) run += part[j][col];   // exclusive seg prefix

#pragma unroll
    for (int i = 0; i < RPT; ++i) {
        run += vals[i];
        ys[(rowbase + (size_t)i * WW) * (size_t)ys_stride] = run;
    }
}

// ---------------------------------------------------------------------------
// Kernel 2: per-row fused — x_s row scan + residual affine + bilinear sample.
// One 512-thread block handles RROWS consecutive rows of one image (so the
// bilinear corner rows overlap in L1/L2). XCD-contiguous swizzle: each of the
// 8 XCDs sweeps a contiguous strip (2 images) in row order.
// ---------------------------------------------------------------------------
__global__ __launch_bounds__(512)
void rowscan_sample_kernel(const float4* __restrict__ im4,
                           const float*  __restrict__ dgx, int dgx_stride,
                           const float*  __restrict__ ys,  int ys_stride,
                           const float*  __restrict__ affine,
                           float4* __restrict__ out4,
                           float*  __restrict__ grid3) {
    // swizzle: 2048 blocks, xcd = blk & 7 gets contiguous strip of 256 tiles
    const int blk  = blockIdx.x;
    const int gt   = (blk & 7) * ((BB * HH / RROWS) / 8) + (blk >> 3);
    const int tile = gt % (HH / RROWS);
    const int b    = gt / (HH / RROWS);

    const int w    = threadIdx.x;          // 0..511
    const int lane = w & 63;
    const int wv   = w >> 6;               // 0..7

    __shared__ float wsum[8];

    const float* Ab = affine + b * 9;
    const float a00 = Ab[0] + 1.f, a01 = Ab[1], a02 = Ab[2];
    const float a10 = Ab[3], a11 = Ab[4] + 1.f, a12 = Ab[5];
    const float a20 = Ab[6], a21 = Ab[7], a22 = Ab[8] + 1.f;

    const size_t ibase = (size_t)b * HH * WW;

    for (int r = 0; r < RROWS; ++r) {
        const int h = tile * RROWS + r;
        const size_t pix = ibase + (size_t)h * WW + w;

        // inclusive scan of dgx across the 512-thread block
        float x = dgx[pix * (size_t)dgx_stride];
#pragma unroll
        for (int off = 1; off < 64; off <<= 1) {
            float n = __shfl_up(x, off, 64);
            if (lane >= off) x += n;
        }
        if (lane == 63) wsum[wv] = x;
        __syncthreads();
        float pref = 0.f;
        for (int j = 0; j < wv; ++j) pref += wsum[j];
        const float xs = x + pref;

        const float ysv = ys[pix * (size_t)ys_stride];

        const float xg = a00 * xs + a01 * ysv + a02;
        const float yg = a10 * xs + a11 * ysv + a12;
        const float wg = a20 * xs + a21 * ysv + a22;

        // bilinear sampling, clamped corner indices exactly as reference
        const int ix = (int)floorf(xg);
        const int iy = (int)floorf(yg);
        const int x0 = min(max(ix,     0), WW - 1);
        const int x1 = min(max(ix + 1, 0), WW - 1);
        const int y0 = min(max(iy,     0), HH - 1);
        const int y1 = min(max(iy + 1, 0), HH - 1);
        const float x0f = (float)x0, x1f = (float)x1;
        const float y0f = (float)y0, y1f = (float)y1;
        const float wa = (x1f - xg) * (y1f - yg);
        const float wb = (x1f - xg) * (yg - y0f);
        const float wc = (xg - x0f) * (y1f - yg);
        const float wd = (xg - x0f) * (yg - y0f);

        const float4 Ia = im4[ibase + (size_t)y0 * WW + x0];
        const float4 Ib = im4[ibase + (size_t)y1 * WW + x0];
        const float4 Ic = im4[ibase + (size_t)y0 * WW + x1];
        const float4 Id = im4[ibase + (size_t)y1 * WW + x1];

        float4 o;
        o.x = wa * Ia.x + wb * Ib.x + wc * Ic.x + wd * Id.x;
        o.y = wa * Ia.y + wb * Ib.y + wc * Ic.y + wd * Id.y;
        o.z = wa * Ia.z + wb * Ib.z + wc * Ic.z + wd * Id.z;
        o.w = wa * Ia.w + wb * Ib.w + wc * Ic.w + wd * Id.w;
        out4[pix] = o;

        grid3[pix * 3 + 0] = xg;
        grid3[pix * 3 + 1] = yg;
        grid3[pix * 3 + 2] = wg;

        __syncthreads();   // wsum reused next row
    }
}

extern "C" void kernel_launch(void* const* d_in, const int* in_sizes, int n_in,
                              void* d_out, int out_size, void* d_ws, size_t ws_size,
                              hipStream_t stream) {
    const float* im      = (const float*)d_in[0];
    const float* defgrad = (const float*)d_in[1];
    const float* affine  = (const float*)d_in[2];

    float* out   = (float*)d_out;
    float* grid3 = out + (size_t)BB * HH * WW * CC;

    const size_t plane = (size_t)BB * HH * WW;       // elements per plane
    const size_t plane_bytes = plane * sizeof(float);

    // scratch planes: prefer planar ws; fall back to stashing inside grid3
    // (each K2 thread reads its own stash slot before overwriting — race-free)
    float* ys;  int ys_stride;
    float* dgx; int dgx_stride;
    if (ws_size >= 2 * plane_bytes) {
        ys  = (float*)d_ws;            ys_stride  = 1;
        dgx = (float*)d_ws + plane;    dgx_stride = 1;
    } else if (ws_size >= plane_bytes) {
        ys  = (float*)d_ws;            ys_stride  = 1;
        dgx = grid3 + 0;               dgx_stride = 3;
    } else {
        ys  = grid3 + 1;               ys_stride  = 3;
        dgx = grid3 + 0;               dgx_stride = 3;
    }

    prep_colscan_kernel<<<BB * (WW / 32), 1024, 0, stream>>>(
        (const float2*)defgrad, dgx, dgx_stride, ys, ys_stride);

    rowscan_sample_kernel<<<BB * (HH / RROWS), 512, 0, stream>>>(
        (const float4*)im, dgx, dgx_stride, ys, ys_stride, affine,
        (float4*)out, grid3);
}